// Round 4
// baseline (213.560 us; speedup 1.0000x reference)
//
#include <hip/hip_runtime.h>
#include <math.h>

#define HH 512
#define WW 1024
#define HWSZ (HH*WW)
#define BB 4
#define TY 8
#define KSIG 11.541560327111707
#define DD_OFF (BB*3*HWSZ)

// One group of source columns (compile-time rx offsets) for one source row.
// Per column: load + derive {r, rr, ec=exp2(-K*r), di} once; then k-outer,
// column-inner evals using table row (D, C=exp2(K*D)) fetched as 4x b128
// broadcast per k. After full unroll all ax selections constant-fold.
template<int... RX>
__device__ __forceinline__ void group_eval(
    const float* __restrict__ pd, const float* __restrict__ p0,
    const float* __restrict__ p1, const float* __restrict__ p2,
    const float (*TAB)[16],
    int x, bool edge, int ryy,
    float* aW, float* aR, float* aG, float* aB, float* aD)
{
    constexpr int N = sizeof...(RX);
    constexpr int rxs[N] = { RX... };

    float d[N], i0[N], i1[N], i2[N];
#pragma unroll
    for (int j = 0; j < N; ++j) {
        const int rx = rxs[j];
        if (edge) {
            const int col = x + rx;
            const bool valid = (unsigned)col < (unsigned)WW;
            const int cc  = col < 0 ? 0 : (col > WW-1 ? WW-1 : col);
            const int cof = cc - x;                 // clamped (safe) offset
            float dv = pd[cof];
            d[j]  = valid ? dv : 0.0f;              // OOB: w<=3.4e-4, no circle
            i0[j] = p0[cof]; i1[j] = p1[cof]; i2[j] = p2[cof];
        } else {
            d[j] = pd[rx]; i0[j] = p0[rx]; i1[j] = p1[rx]; i2[j] = p2[rx];
        }
    }
    float r[N], rr[N], ec[N], di[N];
#pragma unroll
    for (int j = 0; j < N; ++j) {
        r[j]  = fabsf(d[j]);
        rr[j] = fmaxf(d[j]*d[j], 1.0f);
        ec[j] = __builtin_amdgcn_exp2f(r[j] * (float)(-KSIG));
        di[j] = truncf(d[j]);                       // == (float)(int)defocus
    }
#pragma unroll
    for (int k = 0; k < TY; ++k) {
        const int ry = ryy - k;                     // wave-uniform
        const int ay = ry < 0 ? -ry : ry;
        if (ay > 6) continue;                       // uniform skip
        const float4* trow = (const float4*)TAB[ay];
        const float4 t0 = trow[0], t1 = trow[1], t2 = trow[2], t3 = trow[3];
#pragma unroll
        for (int j = 0; j < N; ++j) {
            const int rx = rxs[j];
            const int ax = rx < 0 ? -rx : rx;
            const int aym = (ax <= 4) ? 6 : (ax == 5 ? 4 : 3);  // r^2<=49 cut
            if (ay <= aym) {
                const float D = (ax==0)?t0.x:(ax==1)?t0.z:(ax==2)?t1.x:
                                (ax==3)?t1.z:(ax==4)?t2.x:(ax==5)?t2.z:t3.x;
                const float C = (ax==0)?t0.y:(ax==1)?t0.w:(ax==2)?t1.y:
                                (ax==3)?t1.w:(ax==4)?t2.y:(ax==5)?t2.w:t3.y;
                const float e = C * ec[j];          // exp2(K*(D-r)), factored
                const float w = __builtin_amdgcn_rcpf(fmaf(e, rr[j], rr[j]));
                aW[k] += w;
                aR[k] = fmaf(w, i0[j], aR[k]);
                aG[k] = fmaf(w, i1[j], aG[k]);
                aB[k] = fmaf(w, i2[j], aB[k]);
                aD[k] = fmaxf(aD[k], (r[j] >= D) ? di[j] : -1e30f);
            }
        }
    }
}

__global__ __launch_bounds__(256, 4)
void bokeh_kernel(const float* __restrict__ img,
                  const float* __restrict__ defo,
                  float* __restrict__ out)
{
    // TAB[|ry|][2*ax+{0,1}] = (D, C): D = fl32(sqrt(ry^2+ax^2)) correctly
    // rounded; C = fl32(2^(D*KSIG)). Row = 64B -> 4x ds_read_b128 broadcast.
    __shared__ float TAB[7][16];
    {
        const int t = threadIdx.x;
        if (t < 7*8) {
            const int a = t >> 3, ax = t & 7;
            float D = 1e30f, C = 0.0f;
            if (ax < 7) {
                const double Dd = sqrt((double)(a*a + ax*ax));
                D = (float)Dd;
                C = (float)exp2((double)D * KSIG);
            }
            TAB[a][2*ax]   = D;
            TAB[a][2*ax+1] = C;
        }
    }
    __syncthreads();

    const int lane = threadIdx.x & 63;
    const int wv   = threadIdx.x >> 6;
    const int bx   = blockIdx.x;
    const int x    = bx*64 + lane;                 // lane = x -> coalesced
    const int y0   = blockIdx.y*(4*TY) + wv*TY;    // 8 output rows per thread
    const int b    = blockIdx.z;
    const bool edge = (bx == 0) || (bx == WW/64 - 1);   // wave-uniform

    const float* __restrict__ dP = defo + (size_t)b*HWSZ;
    const float* __restrict__ c0 = img + (size_t)(b*3+0)*HWSZ;
    const float* __restrict__ c1 = img + (size_t)(b*3+1)*HWSZ;
    const float* __restrict__ c2 = img + (size_t)(b*3+2)*HWSZ;

    float aW[TY], aR[TY], aG[TY], aB[TY], aD[TY];
#pragma unroll
    for (int k=0;k<TY;++k){aW[k]=0.f;aR[k]=0.f;aG[k]=0.f;aB[k]=0.f;aD[k]=-1e30f;}

#pragma unroll 1
    for (int ryy = -6; ryy <= TY+5; ++ryy) {       // source rows
        const int sy = y0 + ryy;
        if ((unsigned)sy >= (unsigned)HH) continue;    // uniform (zero pad)
        const int rb = sy*WW + x;
        const float* __restrict__ pd = dP + rb;
        const float* __restrict__ p0 = c0 + rb;
        const float* __restrict__ p1 = c1 + rb;
        const float* __restrict__ p2 = c2 + rb;
        group_eval<-6,-5,-4,-3,-2,-1,0>(pd,p0,p1,p2,TAB,x,edge,ryy,aW,aR,aG,aB,aD);
        group_eval< 1, 2, 3, 4, 5, 6>(pd,p0,p1,p2,TAB,x,edge,ryy,aW,aR,aG,aB,aD);
    }

#pragma unroll
    for (int k=0;k<TY;++k) {
        const int y = y0 + k;
        const float inv = __builtin_amdgcn_rcpf(aW[k]);  // aW >= ~0.0139 always
        const size_t o = (size_t)y*WW + x;
        out[(size_t)(b*3+0)*HWSZ + o] = aR[k]*inv;
        out[(size_t)(b*3+1)*HWSZ + o] = aG[k]*inv;
        out[(size_t)(b*3+2)*HWSZ + o] = aB[k]*inv;
        out[DD_OFF + (size_t)b*HWSZ + o] = aD[k];
    }
}

extern "C" void kernel_launch(void* const* d_in, const int* in_sizes, int n_in,
                              void* d_out, int out_size, void* d_ws, size_t ws_size,
                              hipStream_t stream)
{
    const float* img  = (const float*)d_in[0];
    const float* defo = (const float*)d_in[1];
    float* out = (float*)d_out;
    bokeh_kernel<<<dim3(WW/64, HH/(4*TY), BB), dim3(256,1,1), 0, stream>>>(img, defo, out);
}

// Round 5
// 157.516 us; speedup vs baseline: 1.3558x; 1.3558x over previous
//
#include <hip/hip_runtime.h>
#include <math.h>

#define HH 512
#define WW 1024
#define HWSZ (HH*WW)
#define BB 4
#define TY 8
#define KSIG 11.541560327111707
#define DD_OFF (BB*3*HWSZ)

// One group of source columns (compile-time rx offsets) for one source row,
// against this thread's TY output rows. R3 structure (proven no-spill), with
// the factored sigmoid: e = exp2(K*D)*exp2(-K*r) and w = rcp(e*rr + rr).
template<int... RX>
__device__ __forceinline__ void group_eval(
    const float* __restrict__ pd, const float* __restrict__ p0,
    const float* __restrict__ p1, const float* __restrict__ p2,
    int x, bool edge, int ryy, const float2 (*TT)[8],
    float* aW, float* aR, float* aG, float* aB, float* aD)
{
    constexpr int N = sizeof...(RX);
    constexpr int rxs[N] = { RX... };

    float d[N], i0[N], i1[N], i2[N];
#pragma unroll
    for (int j = 0; j < N; ++j) {
        const int rx = rxs[j];
        if (edge) {
            const int col = x + rx;
            const bool valid = (unsigned)col < (unsigned)WW;
            const int cc  = col < 0 ? 0 : (col > WW-1 ? WW-1 : col);
            const int cof = cc - x;                 // clamped (safe) offset
            float dv = pd[cof];
            d[j]  = valid ? dv : 0.0f;              // OOB: w<=3.4e-4, no circle
            i0[j] = p0[cof]; i1[j] = p1[cof]; i2[j] = p2[cof];
        } else {
            d[j] = pd[rx]; i0[j] = p0[rx]; i1[j] = p1[rx]; i2[j] = p2[rx];
        }
    }
    float r[N], rr[N], ec[N], di[N];
#pragma unroll
    for (int j = 0; j < N; ++j) {
        r[j]  = fabsf(d[j]);
        rr[j] = fmaxf(d[j]*d[j], 1.0f);
        ec[j] = __builtin_amdgcn_exp2f(r[j] * (float)(-KSIG));
        di[j] = truncf(d[j]);                       // == (float)(int)defocus
    }
#pragma unroll
    for (int k = 0; k < TY; ++k) {
        const int ry = ryy - k;                     // wave-uniform
        const unsigned ay = (unsigned)(ry < 0 ? -ry : ry);
        if (ay > 6u) continue;                      // uniform skip
        const float2* row = TT[ry + 6];
#pragma unroll
        for (int j = 0; j < N; ++j) {
            const int rx = rxs[j];
            const int ax = rx < 0 ? -rx : rx;
            const unsigned aym = (ax <= 4) ? 6u : (ax == 5 ? 4u : 3u); // r^2<=49
            if (ay <= aym) {
                const float2 DDv = row[ax];         // broadcast ds_read_b64
                const float e = DDv.y * ec[j];      // exp2(K*(D-r)), factored
                const float w = __builtin_amdgcn_rcpf(fmaf(e, rr[j], rr[j]));
                aW[k] += w;
                aR[k] = fmaf(w, i0[j], aR[k]);
                aG[k] = fmaf(w, i1[j], aG[k]);
                aB[k] = fmaf(w, i2[j], aB[k]);
                aD[k] = fmaxf(aD[k], (r[j] >= DDv.x) ? di[j] : -1e30f);
            }
        }
    }
}

__global__ __launch_bounds__(256, 4)
void bokeh_kernel(const float* __restrict__ img,
                  const float* __restrict__ defo,
                  float* __restrict__ out)
{
    // TT[ry+6][ax] = (D, C): D = fl32(sqrt(ry^2+ax^2)) correctly rounded,
    // C = fl32(2^(K*D)).  Sentinel at ax=7 never read.
    __shared__ float2 TT[13][8];
    {
        const int t = threadIdx.x;
        if (t < 13*8) {
            const int row = t >> 3, ax = t & 7;
            float D = 1e30f, C = 0.0f;
            if (ax < 7) {
                const int ry = row - 6;
                const double Dd = sqrt((double)(ry*ry + ax*ax));
                D = (float)Dd;
                C = (float)exp2((double)D * KSIG);
            }
            TT[row][ax] = make_float2(D, C);
        }
    }
    __syncthreads();

    const int lane = threadIdx.x & 63;
    const int wv   = threadIdx.x >> 6;
    const int bx   = blockIdx.x;
    const int x    = bx*64 + lane;                 // lane = x -> coalesced
    const int y0   = blockIdx.y*(4*TY) + wv*TY;    // 8 output rows per thread
    const int b    = blockIdx.z;
    const bool edge = (bx == 0) || (bx == WW/64 - 1);   // wave-uniform

    const float* __restrict__ dP = defo + (size_t)b*HWSZ;
    const float* __restrict__ c0 = img + (size_t)(b*3+0)*HWSZ;
    const float* __restrict__ c1 = img + (size_t)(b*3+1)*HWSZ;
    const float* __restrict__ c2 = img + (size_t)(b*3+2)*HWSZ;

    float aW[TY], aR[TY], aG[TY], aB[TY], aD[TY];
#pragma unroll
    for (int k=0;k<TY;++k){aW[k]=0.f;aR[k]=0.f;aG[k]=0.f;aB[k]=0.f;aD[k]=-1e30f;}

#pragma unroll 1
    for (int ryy = -6; ryy <= TY+5; ++ryy) {       // source rows (runtime loop)
        const int sy = y0 + ryy;
        if ((unsigned)sy >= (unsigned)HH) continue;    // uniform (zero pad)
        const int rb = sy*WW + x;
        const float* __restrict__ pd = dP + rb;
        const float* __restrict__ p0 = c0 + rb;
        const float* __restrict__ p1 = c1 + rb;
        const float* __restrict__ p2 = c2 + rb;
        group_eval<-6,-5,-4,-3,-2>(pd,p0,p1,p2,x,edge,ryy,TT,aW,aR,aG,aB,aD);
        group_eval<-1, 0, 1, 2, 3>(pd,p0,p1,p2,x,edge,ryy,TT,aW,aR,aG,aB,aD);
        group_eval< 4, 5, 6>      (pd,p0,p1,p2,x,edge,ryy,TT,aW,aR,aG,aB,aD);
    }

#pragma unroll
    for (int k=0;k<TY;++k) {
        const int y = y0 + k;
        const float inv = __builtin_amdgcn_rcpf(aW[k]);  // aW >= ~0.0139 always
        const size_t o = (size_t)y*WW + x;
        out[(size_t)(b*3+0)*HWSZ + o] = aR[k]*inv;
        out[(size_t)(b*3+1)*HWSZ + o] = aG[k]*inv;
        out[(size_t)(b*3+2)*HWSZ + o] = aB[k]*inv;
        out[DD_OFF + (size_t)b*HWSZ + o] = aD[k];
    }
}

extern "C" void kernel_launch(void* const* d_in, const int* in_sizes, int n_in,
                              void* d_out, int out_size, void* d_ws, size_t ws_size,
                              hipStream_t stream)
{
    const float* img  = (const float*)d_in[0];
    const float* defo = (const float*)d_in[1];
    float* out = (float*)d_out;
    bokeh_kernel<<<dim3(WW/64, HH/(4*TY), BB), dim3(256,1,1), 0, stream>>>(img, defo, out);
}